// Round 1
// baseline (308.189 us; speedup 1.0000x reference)
//
#include <hip/hip_runtime.h>

// Problem constants (B=2, C=64, C8=8, H=W=96 -> N=9216)
#define NTOK  9216
#define NBAT  2
#define NTILE1 144          // NTOK/64  (kernel-1 n-tiles)
#define GRID2  (NBAT * 288) // NTOK/32 row-tiles per batch

typedef __attribute__((ext_vector_type(8))) short bf16x8;
typedef __attribute__((ext_vector_type(4))) float f32x4;

__device__ __forceinline__ unsigned short f2bf(float x) {
  unsigned int u = __builtin_bit_cast(unsigned int, x);
  u += 0x7fffu + ((u >> 16) & 1u);   // RNE
  return (unsigned short)(u >> 16);
}

// ---------------------------------------------------------------------------
// Kernel 1: QKV projections.
//   qg[b][n][8]  bf16 (16 B rows -> one K=32 mfma frag, quads>=1 zero-padded)
//   kg[b][n][8]  bf16
//   vg[b][c][n]  bf16 (c-major rows so V A-frags are contiguous in j)
// Block: 256 thr handles one (b, 64-n tile). Wave w computes 20 of the 80
// combined output rows (8 q + 8 k + 64 v); weight indices are wave-uniform
// -> scalar loads.
// ---------------------------------------------------------------------------
__global__ __launch_bounds__(256) void qkv_proj(
    const float* __restrict__ x,
    const float* __restrict__ Wq, const float* __restrict__ bq,
    const float* __restrict__ Wk, const float* __restrict__ bk,
    const float* __restrict__ Wv, const float* __restrict__ bv,
    unsigned short* __restrict__ qg, unsigned short* __restrict__ kg,
    unsigned short* __restrict__ vg)
{
  __shared__ __align__(16) float xlds[64 * 68];   // [cin][n], stride 68 (pad)
  const int bid = blockIdx.x;
  const int b  = bid / NTILE1;
  const int n0 = (bid % NTILE1) * 64;
  const int t  = threadIdx.x;

  // cooperative load of x tile [64 cin][64 n], fp32, coalesced along n
  #pragma unroll
  for (int kk = 0; kk < 4; kk++) {
    int p = t + kk * 256;
    int c = p >> 4, n4 = (p & 15) << 2;
    float4 v = *(const float4*)(x + (size_t)(b * 64 + c) * NTOK + n0 + n4);
    *(float4*)(&xlds[c * 68 + n4]) = v;
  }
  __syncthreads();

  const int n  = t & 63;
  const int cq = __builtin_amdgcn_readfirstlane(t >> 6);  // wave-uniform 0..3

  const float* wrow[20];
  float bias[20];
  #pragma unroll
  for (int r = 0; r < 20; r++) {
    int row = cq * 20 + r;
    if (row < 8)       { wrow[r] = Wq + row * 64;        bias[r] = bq[row]; }
    else if (row < 16) { wrow[r] = Wk + (row - 8) * 64;  bias[r] = bk[row - 8]; }
    else               { wrow[r] = Wv + (row - 16) * 64; bias[r] = bv[row - 16]; }
  }

  float acc[20];
  #pragma unroll
  for (int r = 0; r < 20; r++) acc[r] = 0.f;

  for (int cin = 0; cin < 64; cin++) {
    float xv = xlds[cin * 68 + n];
    #pragma unroll
    for (int r = 0; r < 20; r++)
      acc[r] = fmaf(wrow[r][cin], xv, acc[r]);
  }

  #pragma unroll
  for (int r = 0; r < 20; r++) {
    int row = cq * 20 + r;
    unsigned short ob = f2bf(acc[r] + bias[r]);
    if (row < 8)
      qg[((size_t)b * NTOK + n0 + n) * 8 + row] = ob;
    else if (row < 16)
      kg[((size_t)b * NTOK + n0 + n) * 8 + (row - 8)] = ob;
    else
      vg[(size_t)(b * 64 + (row - 16)) * NTOK + n0 + n] = ob;
  }
}

// ---------------------------------------------------------------------------
// Kernel 2: fused flash attention + epilogue (y = gamma*dyn*softmax(QK^T)V^T + x)
// Block: 128 thr = 2 waves; each wave owns 16 query rows (Mq=32/block).
// Chunk: 64 keys. S^T = K·Q^T via mfma (i ends up in lane&15 -> per-lane
// softmax state); O^T = V·P^T via mfma (same col=i layout, alpha rescale is
// per-lane). P round-trips through a per-wave LDS tile.
// ---------------------------------------------------------------------------
__global__ __launch_bounds__(128) void flash_attn(
    const float* __restrict__ x,
    const unsigned short* __restrict__ qg,
    const unsigned short* __restrict__ kg,
    const unsigned short* __restrict__ vg,
    const float* __restrict__ gamma_p,
    const float* __restrict__ dyn_p,
    float* __restrict__ y)
{
  __shared__ __align__(16) unsigned short v_lds[64 * 72];     // [c][j], stride 72
  __shared__ __align__(16) unsigned short k_lds[64 * 8];      // [j][o], 16 B rows
  __shared__ __align__(16) unsigned short p_lds[2 * 16 * 72]; // per-wave [i][j]

  const int bid  = blockIdx.x;
  const int b    = bid / 288;
  const int rt   = bid % 288;
  const int tid  = threadIdx.x;
  const int w    = tid >> 6;
  const int lane = tid & 63;
  const int i16  = lane & 15;
  const int quad = lane >> 4;
  const int i0   = rt * 32 + w * 16;     // this wave's 16 query rows

  unsigned short* pw = &p_lds[w * 16 * 72];

  // Q B-frag (K=32, real k<8 -> only quad 0 nonzero)
  bf16x8 qf = {};
  if (quad == 0)
    qf = *(const bf16x8*)(qg + ((size_t)b * NTOK + i0 + i16) * 8);

  f32x4 acc[4];
  #pragma unroll
  for (int ct = 0; ct < 4; ct++) acc[ct] = (f32x4){0.f, 0.f, 0.f, 0.f};
  float m = -3.0e38f, l = 0.f;
  const f32x4 z4 = {0.f, 0.f, 0.f, 0.f};

  const size_t vbase = (size_t)b * 64 * NTOK;
  const size_t kbase = (size_t)b * NTOK * 8;

  for (int j0 = 0; j0 < NTOK; j0 += 64) {
    __syncthreads();   // prev chunk's tile reads complete before overwrite

    // stage V tile (64c x 64j bf16 = 8 KB) and K tile (64j x 16 B = 1 KB)
    #pragma unroll
    for (int kk = 0; kk < 4; kk++) {
      int p = tid + kk * 128;
      int c = p >> 3, seg = p & 7;
      uint4 val = *(const uint4*)(vg + vbase + (size_t)c * NTOK + j0 + seg * 8);
      *(uint4*)(&v_lds[c * 72 + seg * 8]) = val;
    }
    if (tid < 64) {
      uint4 val = *(const uint4*)(kg + kbase + (size_t)(j0 + tid) * 8);
      *(uint4*)(&k_lds[tid * 8]) = val;
    }
    __syncthreads();

    // ---- S^T tiles: st[jt] holds e[i = i16][j = j0 + jt*16 + quad*4 + r]
    f32x4 st[4];
    #pragma unroll
    for (int jt = 0; jt < 4; jt++) {
      bf16x8 kf = {};
      if (quad == 0)
        kf = *(const bf16x8*)(&k_lds[(jt * 16 + i16) * 8]);
      st[jt] = __builtin_amdgcn_mfma_f32_16x16x32_bf16(kf, qf, z4, 0, 0, 0);
    }

    // ---- online softmax for row i16 (this lane holds 16 of its 64 chunk e's)
    float emax = st[0][0];
    #pragma unroll
    for (int jt = 0; jt < 4; jt++)
      #pragma unroll
      for (int r = 0; r < 4; r++) emax = fmaxf(emax, st[jt][r]);
    emax = fmaxf(emax, __shfl_xor(emax, 16));
    emax = fmaxf(emax, __shfl_xor(emax, 32));
    float mn    = fmaxf(m, emax);
    float alpha = __expf(m - mn);
    float ps = 0.f;
    #pragma unroll
    for (int jt = 0; jt < 4; jt++) {
      float p0 = __expf(st[jt][0] - mn);
      float p1 = __expf(st[jt][1] - mn);
      float p2 = __expf(st[jt][2] - mn);
      float p3 = __expf(st[jt][3] - mn);
      ps += (p0 + p1) + (p2 + p3);
      unsigned int lo = (unsigned int)f2bf(p0) | ((unsigned int)f2bf(p1) << 16);
      unsigned int hi = (unsigned int)f2bf(p2) | ((unsigned int)f2bf(p3) << 16);
      *(uint2*)(&pw[i16 * 72 + jt * 16 + quad * 4]) = make_uint2(lo, hi);
    }
    ps += __shfl_xor(ps, 16);
    ps += __shfl_xor(ps, 32);
    l = l * alpha + ps;
    m = mn;
    #pragma unroll
    for (int ct = 0; ct < 4; ct++)
      #pragma unroll
      for (int r = 0; r < 4; r++) acc[ct][r] *= alpha;

    __syncthreads();   // P tile visible wave-wide; tiles still intact

    // ---- O^T += V · P^T  (4 c-tiles x 2 j-halves)
    bf16x8 pf0 = *(const bf16x8*)(&pw[i16 * 72 + quad * 8]);
    bf16x8 pf1 = *(const bf16x8*)(&pw[i16 * 72 + 32 + quad * 8]);
    #pragma unroll
    for (int ct = 0; ct < 4; ct++) {
      bf16x8 vf0 = *(const bf16x8*)(&v_lds[(ct * 16 + i16) * 72 + quad * 8]);
      bf16x8 vf1 = *(const bf16x8*)(&v_lds[(ct * 16 + i16) * 72 + 32 + quad * 8]);
      acc[ct] = __builtin_amdgcn_mfma_f32_16x16x32_bf16(vf0, pf0, acc[ct], 0, 0, 0);
      acc[ct] = __builtin_amdgcn_mfma_f32_16x16x32_bf16(vf1, pf1, acc[ct], 0, 0, 0);
    }
  }

  // ---- epilogue: y = gamma*dyn/l * O^T + x
  const float scale = gamma_p[0] * dyn_p[0] / l;
  #pragma unroll
  for (int ct = 0; ct < 4; ct++)
    #pragma unroll
    for (int r = 0; r < 4; r++) {
      int c = ct * 16 + quad * 4 + r;
      size_t a = (size_t)(b * 64 + c) * NTOK + i0 + i16;
      y[a] = acc[ct][r] * scale + x[a];
    }
}

// ---------------------------------------------------------------------------
extern "C" void kernel_launch(void* const* d_in, const int* in_sizes, int n_in,
                              void* d_out, int out_size, void* d_ws, size_t ws_size,
                              hipStream_t stream) {
  const float* x     = (const float*)d_in[0];
  const float* Wq    = (const float*)d_in[1];
  const float* bq    = (const float*)d_in[2];
  const float* Wk    = (const float*)d_in[3];
  const float* bk    = (const float*)d_in[4];
  const float* Wv    = (const float*)d_in[5];
  const float* bv    = (const float*)d_in[6];
  const float* gamma = (const float*)d_in[7];
  const float* dyn   = (const float*)d_in[8];
  float* y = (float*)d_out;

  // workspace: qg | kg | vg  (bf16)
  unsigned short* qg = (unsigned short*)d_ws;              // B*N*8
  unsigned short* kg = qg + (size_t)NBAT * NTOK * 8;       // B*N*8
  unsigned short* vg = kg + (size_t)NBAT * NTOK * 8;       // B*64*N

  qkv_proj<<<NBAT * NTILE1, 256, 0, stream>>>(x, Wq, bq, Wk, bk, Wv, bv, qg, kg, vg);
  flash_attn<<<GRID2, 128, 0, stream>>>(x, qg, kg, vg, gamma, dyn, y);
}